// Round 1
// baseline (233.144 us; speedup 1.0000x reference)
//
#include <hip/hip_runtime.h>
#include <math.h>

#define TS 32768              // table size (fits in 128 KB of d_ws; L2-resident)
#define NPTS 16384            // N per row
#define NROWS 256             // B

// numerically stable softplus
__device__ __forceinline__ float softplus(float x) {
    float ax = fabsf(x);
    return fmaxf(x, 0.0f) + log1pf(__expf(-ax));
}

// Kernel 1: tabulate dg(t) = MLP(t) on uniform grid over [0, 10].
// Weights are wave-uniform -> compiler emits scalar (s_load) reads.
__global__ __launch_bounds__(256) void build_table(
    const float* __restrict__ W1, const float* __restrict__ b1,
    const float* __restrict__ W2, const float* __restrict__ b2,
    const float* __restrict__ W3, const float* __restrict__ b3,
    const float* __restrict__ W4, const float* __restrict__ b4,
    const float* __restrict__ W5, const float* __restrict__ b5,
    float* __restrict__ table)
{
    int i = blockIdx.x * blockDim.x + threadIdx.x;
    if (i >= TS) return;
    float t = 10.0f * (float)i / (float)(TS - 1);

    float h1[32];
#pragma unroll
    for (int j = 0; j < 32; ++j)
        h1[j] = softplus(fmaf(t, W1[j], b1[j]));

    float h2[64];
#pragma unroll
    for (int j = 0; j < 64; ++j) {
        float acc = b2[j];
#pragma unroll
        for (int k = 0; k < 32; ++k)
            acc = fmaf(h1[k], W2[j * 32 + k], acc);
        h2[j] = softplus(acc);
    }

    float h3[64];
#pragma unroll
    for (int j = 0; j < 64; ++j) {
        float acc = b3[j];
#pragma unroll
        for (int k = 0; k < 64; ++k)
            acc = fmaf(h2[k], W3[j * 64 + k], acc);
        h3[j] = softplus(acc);
    }

    float h4[32];
#pragma unroll
    for (int j = 0; j < 32; ++j) {
        float acc = b4[j];
#pragma unroll
        for (int k = 0; k < 64; ++k)
            acc = fmaf(h3[k], W4[j * 64 + k], acc);
        h4[j] = softplus(acc);
    }

    float acc5 = b5[0];
#pragma unroll
    for (int k = 0; k < 32; ++k)
        acc5 = fmaf(h4[k], W5[k], acc5);

    table[i] = softplus(acc5) + 1.0f;
}

__device__ __forceinline__ float dg_lookup(const float* __restrict__ tab, float t) {
    const float scale = (float)(TS - 1) / 10.0f;
    float x = t * scale;
    x = fminf(fmaxf(x, 0.0f), (float)(TS - 1));
    int i = (int)x;
    if (i > TS - 2) i = TS - 2;
    float f = x - (float)i;
    float a = tab[i];
    float b = tab[i + 1];
    return fmaf(b - a, f, a);
}

// Kernel 2: per-row cumulative trapezoid with table-interpolated dg.
// One block per row: 1024 threads x 16 elements = 16384.
__global__ __launch_bounds__(1024) void integrate(
    const float* __restrict__ t,
    const float* __restrict__ table,
    float* __restrict__ out)
{
    const int row = blockIdx.x;
    const float* tr = t + (size_t)row * NPTS;
    float*       gr = out + (size_t)row * NPTS;
    const int tid  = threadIdx.x;
    const int base = tid * 16;

    // load 16 contiguous t values (64B-aligned float4s)
    float tv[16];
    const float4* tv4 = (const float4*)(tr + base);
#pragma unroll
    for (int q = 0; q < 4; ++q) {
        float4 v = tv4[q];
        tv[q * 4 + 0] = v.x; tv[q * 4 + 1] = v.y;
        tv[q * 4 + 2] = v.z; tv[q * 4 + 3] = v.w;
    }
    // previous t (for base==0 use t[0] -> dt=0 -> inc=0, matching g[0]=0)
    float tprev = (base == 0) ? tv[0] : tr[base - 1];

    // per-thread serial inclusive scan of trapezoid increments
    float run[16];
    float s  = 0.0f;
    float tp = tprev;
    float dp = dg_lookup(table, tprev);
#pragma unroll
    for (int q = 0; q < 16; ++q) {
        float dc = dg_lookup(table, tv[q]);
        s += 0.5f * (dc + dp) * (tv[q] - tp);
        run[q] = s;
        tp = tv[q];
        dp = dc;
    }

    // wave-level (64-lane) inclusive scan of per-thread totals
    const int lane = tid & 63;
    const int wave = tid >> 6;
    float v = s;
#pragma unroll
    for (int d = 1; d < 64; d <<= 1) {
        float u = __shfl_up(v, d, 64);
        if (lane >= d) v += u;
    }

    // block-level scan across 16 waves
    __shared__ float wsum[16];
    if (lane == 63) wsum[wave] = v;
    __syncthreads();
    float woff = 0.0f;
#pragma unroll
    for (int w = 0; w < 16; ++w)
        woff += (w < wave) ? wsum[w] : 0.0f;

    const float texcl = woff + (v - s);   // exclusive prefix for this thread

    float4* g4 = (float4*)(gr + base);
#pragma unroll
    for (int q = 0; q < 4; ++q) {
        float4 o;
        o.x = texcl + run[q * 4 + 0];
        o.y = texcl + run[q * 4 + 1];
        o.z = texcl + run[q * 4 + 2];
        o.w = texcl + run[q * 4 + 3];
        g4[q] = o;
    }
}

extern "C" void kernel_launch(void* const* d_in, const int* in_sizes, int n_in,
                              void* d_out, int out_size, void* d_ws, size_t ws_size,
                              hipStream_t stream)
{
    const float* t  = (const float*)d_in[0];
    const float* W1 = (const float*)d_in[1];
    const float* b1 = (const float*)d_in[2];
    const float* W2 = (const float*)d_in[3];
    const float* b2 = (const float*)d_in[4];
    const float* W3 = (const float*)d_in[5];
    const float* b3 = (const float*)d_in[6];
    const float* W4 = (const float*)d_in[7];
    const float* b4 = (const float*)d_in[8];
    const float* W5 = (const float*)d_in[9];
    const float* b5 = (const float*)d_in[10];
    float* table = (float*)d_ws;
    float* out   = (float*)d_out;

    build_table<<<TS / 256, 256, 0, stream>>>(W1, b1, W2, b2, W3, b3, W4, b4, W5, b5, table);
    integrate<<<NROWS, 1024, 0, stream>>>(t, table, out);
}

// Round 2
// 220.735 us; speedup vs baseline: 1.0562x; 1.0562x over previous
//
#include <hip/hip_runtime.h>
#include <math.h>

#define TS 16384              // table size (64 KB -> fits static LDS)
#define NPTS 16384            // N per row
#define NROWS 256             // B

// softplus via hardware transcendentals (v_exp_f32 / v_log_f32).
// log(1+e) with e in (0,1]: when e < 2^-24 result rounds to 0 vs true ~e;
// absolute error <= 6e-8 in dg -- negligible vs the 0.32 absmax threshold.
__device__ __forceinline__ float softplus(float x) {
    float ax = fabsf(x);
    return fmaxf(x, 0.0f) + __logf(1.0f + __expf(-ax));
}

// Kernel 1: tabulate dg(t) = MLP(t) on uniform grid over [0, 10].
// block=64, grid=256 -> one wave per CU, all CUs busy.
// __launch_bounds__(64,1): allow high VGPR count so h2[64]/h3[64] stay
// in registers (R0's default target spilled ~8 MB of scratch at VGPR=60).
__global__ __launch_bounds__(64, 1) void build_table(
    const float* __restrict__ W1, const float* __restrict__ b1,
    const float* __restrict__ W2, const float* __restrict__ b2,
    const float* __restrict__ W3, const float* __restrict__ b3,
    const float* __restrict__ W4, const float* __restrict__ b4,
    const float* __restrict__ W5, const float* __restrict__ b5,
    float* __restrict__ table)
{
    int i = blockIdx.x * blockDim.x + threadIdx.x;
    if (i >= TS) return;
    float t = 10.0f * (float)i / (float)(TS - 1);

    float h1[32];
#pragma unroll
    for (int j = 0; j < 32; ++j)
        h1[j] = softplus(fmaf(t, W1[j], b1[j]));

    float h2[64];
#pragma unroll
    for (int j = 0; j < 64; ++j) {
        float acc = b2[j];
#pragma unroll
        for (int k = 0; k < 32; ++k)
            acc = fmaf(h1[k], W2[j * 32 + k], acc);
        h2[j] = softplus(acc);
    }

    float h3[64];
#pragma unroll
    for (int j = 0; j < 64; ++j) {
        float acc = b3[j];
#pragma unroll
        for (int k = 0; k < 64; ++k)
            acc = fmaf(h2[k], W3[j * 64 + k], acc);
        h3[j] = softplus(acc);
    }

    float h4[32];
#pragma unroll
    for (int j = 0; j < 32; ++j) {
        float acc = b4[j];
#pragma unroll
        for (int k = 0; k < 64; ++k)
            acc = fmaf(h3[k], W4[j * 64 + k], acc);
        h4[j] = softplus(acc);
    }

    float acc5 = b5[0];
#pragma unroll
    for (int k = 0; k < 32; ++k)
        acc5 = fmaf(h4[k], W5[k], acc5);

    table[i] = softplus(acc5) + 1.0f;
}

__device__ __forceinline__ float dg_lookup(const float* __restrict__ tab, float t) {
    const float scale = (float)(TS - 1) / 10.0f;
    float x = t * scale;
    x = fminf(fmaxf(x, 0.0f), (float)(TS - 1));
    int i = (int)x;
    if (i > TS - 2) i = TS - 2;
    float f = x - (float)i;
    float a = tab[i];
    float b = tab[i + 1];
    return fmaf(b - a, f, a);
}

// Kernel 2: per-row cumulative trapezoid with LDS-resident dg table.
// One block per row: 1024 threads x 16 elements = 16384.
// Table gathers from LDS (~2-way avg bank conflicts = free) instead of
// scattered 4B L2 gathers (R0: ~1 GB of L2->L1 line traffic).
__global__ __launch_bounds__(1024) void integrate(
    const float* __restrict__ t,
    const float* __restrict__ table,
    float* __restrict__ out)
{
    __shared__ float tab[TS];   // 64 KB

    const int tid = threadIdx.x;
    // cooperative coalesced table load: 16 floats/thread as float4
    {
        const float4* src = (const float4*)table;
        float4* dst = (float4*)tab;
#pragma unroll
        for (int q = 0; q < TS / 4 / 1024; ++q)
            dst[q * 1024 + tid] = src[q * 1024 + tid];
    }
    __syncthreads();

    const int row = blockIdx.x;
    const float* tr = t + (size_t)row * NPTS;
    float*       gr = out + (size_t)row * NPTS;
    const int base = tid * 16;

    // load 16 contiguous t values (64B-aligned float4s)
    float tv[16];
    const float4* tv4 = (const float4*)(tr + base);
#pragma unroll
    for (int q = 0; q < 4; ++q) {
        float4 v = tv4[q];
        tv[q * 4 + 0] = v.x; tv[q * 4 + 1] = v.y;
        tv[q * 4 + 2] = v.z; tv[q * 4 + 3] = v.w;
    }
    // previous t (for base==0 use t[0] -> dt=0 -> inc=0, matching g[0]=0)
    float tprev = (base == 0) ? tv[0] : tr[base - 1];

    // per-thread serial inclusive scan of trapezoid increments
    float run[16];
    float s  = 0.0f;
    float tp = tprev;
    float dp = dg_lookup(tab, tprev);
#pragma unroll
    for (int q = 0; q < 16; ++q) {
        float dc = dg_lookup(tab, tv[q]);
        s += 0.5f * (dc + dp) * (tv[q] - tp);
        run[q] = s;
        tp = tv[q];
        dp = dc;
    }

    // wave-level (64-lane) inclusive scan of per-thread totals
    const int lane = tid & 63;
    const int wave = tid >> 6;
    float v = s;
#pragma unroll
    for (int d = 1; d < 64; d <<= 1) {
        float u = __shfl_up(v, d, 64);
        if (lane >= d) v += u;
    }

    // block-level scan across 16 waves
    __shared__ float wsum[16];
    if (lane == 63) wsum[wave] = v;
    __syncthreads();
    float woff = 0.0f;
#pragma unroll
    for (int w = 0; w < 16; ++w)
        woff += (w < wave) ? wsum[w] : 0.0f;

    const float texcl = woff + (v - s);   // exclusive prefix for this thread

    float4* g4 = (float4*)(gr + base);
#pragma unroll
    for (int q = 0; q < 4; ++q) {
        float4 o;
        o.x = texcl + run[q * 4 + 0];
        o.y = texcl + run[q * 4 + 1];
        o.z = texcl + run[q * 4 + 2];
        o.w = texcl + run[q * 4 + 3];
        g4[q] = o;
    }
}

extern "C" void kernel_launch(void* const* d_in, const int* in_sizes, int n_in,
                              void* d_out, int out_size, void* d_ws, size_t ws_size,
                              hipStream_t stream)
{
    const float* t  = (const float*)d_in[0];
    const float* W1 = (const float*)d_in[1];
    const float* b1 = (const float*)d_in[2];
    const float* W2 = (const float*)d_in[3];
    const float* b2 = (const float*)d_in[4];
    const float* W3 = (const float*)d_in[5];
    const float* b3 = (const float*)d_in[6];
    const float* W4 = (const float*)d_in[7];
    const float* b4 = (const float*)d_in[8];
    const float* W5 = (const float*)d_in[9];
    const float* b5 = (const float*)d_in[10];
    float* table = (float*)d_ws;
    float* out   = (float*)d_out;

    build_table<<<TS / 64, 64, 0, stream>>>(W1, b1, W2, b2, W3, b3, W4, b4, W5, b5, table);
    integrate<<<NROWS, 1024, 0, stream>>>(t, table, out);
}

// Round 3
// 139.367 us; speedup vs baseline: 1.6729x; 1.5838x over previous
//
#include <hip/hip_runtime.h>
#include <math.h>

#define TS 16384              // table size (64 KB)
#define NPTS 16384            // N per row
#define NROWS 256             // B

// softplus via hardware transcendentals (v_exp_f32 / v_log_f32).
__device__ __forceinline__ float softplus(float x) {
    float ax = fabsf(x);
    return fmaxf(x, 0.0f) + __logf(1.0f + __expf(-ax));
}

// LDS layout offsets (floats) for the staged weights
#define OFF_W1 0            // 32
#define OFF_B1 32           // 32
#define OFF_W2 64           // 2048
#define OFF_B2 2112         // 64
#define OFF_W3 2176         // 4096
#define OFF_B3 6272         // 64
#define OFF_W4 6336         // 2048
#define OFF_B4 8384         // 32
#define OFF_W5 8416         // 32
#define OFF_B5 8448         // 1
#define WTOT   8449

// Kernel 1: tabulate dg(t) = MLP(t) on uniform grid over [0, 10].
// block=64, grid=256 -> ONE wave per CU (DS broadcast traffic is per-wave;
// more waves/CU would multiply DS-pipe load).
// R1 lesson: wave-uniform weight reads go through SMEM, which returns
// out-of-order -> compiler serializes with lgkmcnt(0) per batch -> ~40 cyc
// per weight = 135 us. Staging weights in LDS turns them into in-order
// ds_read_b128 broadcasts that the compiler pipelines fine-grained.
__global__ __launch_bounds__(64, 1) void build_table(
    const float* __restrict__ W1, const float* __restrict__ b1,
    const float* __restrict__ W2, const float* __restrict__ b2,
    const float* __restrict__ W3, const float* __restrict__ b3,
    const float* __restrict__ W4, const float* __restrict__ b4,
    const float* __restrict__ W5, const float* __restrict__ b5,
    float* __restrict__ table)
{
    __shared__ float w[WTOT];
    const int tid = threadIdx.x;  // 0..63

    // ---- stage weights into LDS (coalesced float4 for the big matrices) ----
    {
        float4* dst2 = (float4*)(w + OFF_W2);
        const float4* src2 = (const float4*)W2;
#pragma unroll
        for (int q = 0; q < 2048 / 4 / 64; ++q)        // 8 iters
            dst2[q * 64 + tid] = src2[q * 64 + tid];

        float4* dst3 = (float4*)(w + OFF_W3);
        const float4* src3 = (const float4*)W3;
#pragma unroll
        for (int q = 0; q < 4096 / 4 / 64; ++q)        // 16 iters
            dst3[q * 64 + tid] = src3[q * 64 + tid];

        float4* dst4 = (float4*)(w + OFF_W4);
        const float4* src4 = (const float4*)W4;
#pragma unroll
        for (int q = 0; q < 2048 / 4 / 64; ++q)        // 8 iters
            dst4[q * 64 + tid] = src4[q * 64 + tid];

        if (tid < 32) {
            w[OFF_W1 + tid] = W1[tid];
            w[OFF_B1 + tid] = b1[tid];
            w[OFF_B4 + tid] = b4[tid];
            w[OFF_W5 + tid] = W5[tid];
        }
        w[OFF_B2 + tid] = b2[tid];   // 64
        w[OFF_B3 + tid] = b3[tid];   // 64
        if (tid == 0) w[OFF_B5] = b5[0];
    }
    __syncthreads();

    int i = blockIdx.x * 64 + tid;
    float t = 10.0f * (float)i / (float)(TS - 1);

    float h1[32];
#pragma unroll
    for (int j = 0; j < 32; ++j)
        h1[j] = softplus(fmaf(t, w[OFF_W1 + j], w[OFF_B1 + j]));

    float h2[64];
#pragma unroll
    for (int j = 0; j < 64; ++j) {
        float acc = w[OFF_B2 + j];
#pragma unroll
        for (int k = 0; k < 32; ++k)
            acc = fmaf(h1[k], w[OFF_W2 + j * 32 + k], acc);
        h2[j] = softplus(acc);
    }

    float h3[64];
#pragma unroll
    for (int j = 0; j < 64; ++j) {
        float acc = w[OFF_B3 + j];
#pragma unroll
        for (int k = 0; k < 64; ++k)
            acc = fmaf(h2[k], w[OFF_W3 + j * 64 + k], acc);
        h3[j] = softplus(acc);
    }

    float h4[32];
#pragma unroll
    for (int j = 0; j < 32; ++j) {
        float acc = w[OFF_B4 + j];
#pragma unroll
        for (int k = 0; k < 64; ++k)
            acc = fmaf(h3[k], w[OFF_W4 + j * 64 + k], acc);
        h4[j] = softplus(acc);
    }

    float acc5 = w[OFF_B5];
#pragma unroll
    for (int k = 0; k < 32; ++k)
        acc5 = fmaf(h4[k], w[OFF_W5 + k], acc5);

    table[i] = softplus(acc5) + 1.0f;
}

__device__ __forceinline__ float dg_lookup(const float* __restrict__ tab, float t) {
    const float scale = (float)(TS - 1) / 10.0f;
    float x = t * scale;
    x = fminf(fmaxf(x, 0.0f), (float)(TS - 1));
    int i = (int)x;
    if (i > TS - 2) i = TS - 2;
    float f = x - (float)i;
    float a = tab[i];
    float b = tab[i + 1];
    return fmaf(b - a, f, a);
}

// Kernel 2: per-row cumulative trapezoid with LDS-resident dg table.
// One block per row: 1024 threads x 16 elements = 16384.
__global__ __launch_bounds__(1024) void integrate(
    const float* __restrict__ t,
    const float* __restrict__ table,
    float* __restrict__ out)
{
    __shared__ float tab[TS];   // 64 KB

    const int tid = threadIdx.x;
    // cooperative coalesced table load: float4s
    {
        const float4* src = (const float4*)table;
        float4* dst = (float4*)tab;
#pragma unroll
        for (int q = 0; q < TS / 4 / 1024; ++q)
            dst[q * 1024 + tid] = src[q * 1024 + tid];
    }
    __syncthreads();

    const int row = blockIdx.x;
    const float* tr = t + (size_t)row * NPTS;
    float*       gr = out + (size_t)row * NPTS;
    const int base = tid * 16;

    // load 16 contiguous t values (64B-aligned float4s)
    float tv[16];
    const float4* tv4 = (const float4*)(tr + base);
#pragma unroll
    for (int q = 0; q < 4; ++q) {
        float4 v = tv4[q];
        tv[q * 4 + 0] = v.x; tv[q * 4 + 1] = v.y;
        tv[q * 4 + 2] = v.z; tv[q * 4 + 3] = v.w;
    }
    // previous t (for base==0 use t[0] -> dt=0 -> inc=0, matching g[0]=0)
    float tprev = (base == 0) ? tv[0] : tr[base - 1];

    // per-thread serial inclusive scan of trapezoid increments
    float run[16];
    float s  = 0.0f;
    float tp = tprev;
    float dp = dg_lookup(tab, tprev);
#pragma unroll
    for (int q = 0; q < 16; ++q) {
        float dc = dg_lookup(tab, tv[q]);
        s += 0.5f * (dc + dp) * (tv[q] - tp);
        run[q] = s;
        tp = tv[q];
        dp = dc;
    }

    // wave-level (64-lane) inclusive scan of per-thread totals
    const int lane = tid & 63;
    const int wave = tid >> 6;
    float v = s;
#pragma unroll
    for (int d = 1; d < 64; d <<= 1) {
        float u = __shfl_up(v, d, 64);
        if (lane >= d) v += u;
    }

    // block-level scan across 16 waves
    __shared__ float wsum[16];
    if (lane == 63) wsum[wave] = v;
    __syncthreads();
    float woff = 0.0f;
#pragma unroll
    for (int w = 0; w < 16; ++w)
        woff += (w < wave) ? wsum[w] : 0.0f;

    const float texcl = woff + (v - s);   // exclusive prefix for this thread

    float4* g4 = (float4*)(gr + base);
#pragma unroll
    for (int q = 0; q < 4; ++q) {
        float4 o;
        o.x = texcl + run[q * 4 + 0];
        o.y = texcl + run[q * 4 + 1];
        o.z = texcl + run[q * 4 + 2];
        o.w = texcl + run[q * 4 + 3];
        g4[q] = o;
    }
}

extern "C" void kernel_launch(void* const* d_in, const int* in_sizes, int n_in,
                              void* d_out, int out_size, void* d_ws, size_t ws_size,
                              hipStream_t stream)
{
    const float* t  = (const float*)d_in[0];
    const float* W1 = (const float*)d_in[1];
    const float* b1 = (const float*)d_in[2];
    const float* W2 = (const float*)d_in[3];
    const float* b2 = (const float*)d_in[4];
    const float* W3 = (const float*)d_in[5];
    const float* b3 = (const float*)d_in[6];
    const float* W4 = (const float*)d_in[7];
    const float* b4 = (const float*)d_in[8];
    const float* W5 = (const float*)d_in[9];
    const float* b5 = (const float*)d_in[10];
    float* table = (float*)d_ws;
    float* out   = (float*)d_out;

    build_table<<<TS / 64, 64, 0, stream>>>(W1, b1, W2, b2, W3, b3, W4, b4, W5, b5, table);
    integrate<<<NROWS, 1024, 0, stream>>>(t, table, out);
}

// Round 4
// 101.740 us; speedup vs baseline: 2.2916x; 1.3698x over previous
//
#include <hip/hip_runtime.h>
#include <math.h>

#define TS 8192               // table size (32 KB -> fits integrate's LDS easily)
#define NPTS 16384            // N per row
#define NROWS 256             // B

// softplus via hardware transcendentals (v_exp_f32 / v_log_f32)
__device__ __forceinline__ float softplus(float x) {
    float ax = fabsf(x);
    return fmaxf(x, 0.0f) + __logf(1.0f + __expf(-ax));
}

// LDS layout offsets (floats) for the staged weights
#define OFF_W1 0            // 32
#define OFF_B1 32           // 32
#define OFF_W2 64           // 2048  (16B aligned: 64*4=256)
#define OFF_B2 2112         // 64
#define OFF_W3 2176         // 4096  (16B aligned)
#define OFF_B3 6272         // 64
#define OFF_W4 6336         // 2048  (16B aligned)
#define OFF_B4 8384         // 32
#define OFF_W5 8416         // 32
#define OFF_B5 8448         // 1
#define WTOT   8449

// Kernel 1: tabulate dg(t) = MLP(t) on uniform grid over [0,10].
// R3 lesson: one wave per CU doing ALL 2064 weight ds_reads is a latency
// chain (~58 cyc/read observed). Restructure: block=512 (8 waves) computes
// 32 entries; lane&31 = entry, lane>>5 = k-half, wave = j-slice. Each wave
// reads only its 1/16 of the weights; the two k-halves share one broadcast
// ds_read (2 distinct addresses = free 2-way). Layer exchange via padded
// LDS hbuf (stride 65 -> conflict-free), halves combined via shfl_xor(32).
__global__ __launch_bounds__(512, 2) void build_table(
    const float* __restrict__ W1, const float* __restrict__ b1,
    const float* __restrict__ W2, const float* __restrict__ b2,
    const float* __restrict__ W3, const float* __restrict__ b3,
    const float* __restrict__ W4, const float* __restrict__ b4,
    const float* __restrict__ W5, const float* __restrict__ b5,
    float* __restrict__ table)
{
    __shared__ float w[WTOT];
    __shared__ float hbuf[32][65];   // 32 entries x up to 64 hidden, +1 pad

    const int tid  = threadIdx.x;        // 0..511
    const int lane = tid & 63;
    const int wave = tid >> 6;           // 0..7
    const int half = lane >> 5;          // 0..1 (k-dimension split)
    const int e    = lane & 31;          // entry within block

    // ---- stage weights into LDS (coalesced float4) ----
    {
        float4*       d2 = (float4*)(w + OFF_W2);
        const float4* s2 = (const float4*)W2;
        d2[tid] = s2[tid];                               // 512 f4
        float4*       d3 = (float4*)(w + OFF_W3);
        const float4* s3 = (const float4*)W3;
        d3[tid] = s3[tid]; d3[512 + tid] = s3[512 + tid]; // 1024 f4
        float4*       d4 = (float4*)(w + OFF_W4);
        const float4* s4 = (const float4*)W4;
        d4[tid] = s4[tid];                               // 512 f4
        if (tid < 32) {
            w[OFF_W1 + tid] = W1[tid];
            w[OFF_B1 + tid] = b1[tid];
            w[OFF_B4 + tid] = b4[tid];
            w[OFF_W5 + tid] = W5[tid];
        }
        if (tid < 64) {
            w[OFF_B2 + tid] = b2[tid];
            w[OFF_B3 + tid] = b3[tid];
        }
        if (tid == 0) w[OFF_B5] = b5[0];
    }
    __syncthreads();

    const int   i = blockIdx.x * 32 + e;
    const float t = 10.0f * (float)i / (float)(TS - 1);

    // ---- L1: 1 -> 32. wave handles j in [wave*4, wave*4+4). both halves
    // compute (redundant), half==0 writes.
    {
#pragma unroll
        for (int jj = 0; jj < 4; ++jj) {
            int j = wave * 4 + jj;
            float v = softplus(fmaf(t, w[OFF_W1 + j], w[OFF_B1 + j]));
            if (half == 0) hbuf[e][j] = v;
        }
    }
    __syncthreads();

    // ---- L2: 32 -> 64. k-half = 16 each, wave handles 8 j's.
    {
        float hr[16];
        const float* hp = &hbuf[e][half * 16];
#pragma unroll
        for (int k = 0; k < 16; ++k) hr[k] = hp[k];
        float acc[8];
#pragma unroll
        for (int jj = 0; jj < 8; ++jj) {
            int j = wave * 8 + jj;
            const float* wp = &w[OFF_W2 + j * 32 + half * 16];
            float a = 0.0f;
#pragma unroll
            for (int k = 0; k < 16; ++k) a = fmaf(hr[k], wp[k], a);
            acc[jj] = a;
        }
        __syncthreads();   // reads of h1 done
#pragma unroll
        for (int jj = 0; jj < 8; ++jj) {
            int j = wave * 8 + jj;
            float s = acc[jj] + __shfl_xor(acc[jj], 32, 64);
            float v = softplus(s + w[OFF_B2 + j]);
            if (half == 0) hbuf[e][j] = v;
        }
    }
    __syncthreads();

    // ---- L3: 64 -> 64. k-half = 32 each, wave handles 8 j's.
    {
        float hr[32];
        const float* hp = &hbuf[e][half * 32];
#pragma unroll
        for (int k = 0; k < 32; ++k) hr[k] = hp[k];
        float acc[8];
#pragma unroll
        for (int jj = 0; jj < 8; ++jj) {
            int j = wave * 8 + jj;
            const float* wp = &w[OFF_W3 + j * 64 + half * 32];
            float a = 0.0f;
#pragma unroll
            for (int k = 0; k < 32; ++k) a = fmaf(hr[k], wp[k], a);
            acc[jj] = a;
        }
        __syncthreads();
#pragma unroll
        for (int jj = 0; jj < 8; ++jj) {
            int j = wave * 8 + jj;
            float s = acc[jj] + __shfl_xor(acc[jj], 32, 64);
            float v = softplus(s + w[OFF_B3 + j]);
            if (half == 0) hbuf[e][j] = v;
        }
    }
    __syncthreads();

    // ---- L4: 64 -> 32. k-half = 32 each, wave handles 4 j's.
    {
        float hr[32];
        const float* hp = &hbuf[e][half * 32];
#pragma unroll
        for (int k = 0; k < 32; ++k) hr[k] = hp[k];
        float acc[4];
#pragma unroll
        for (int jj = 0; jj < 4; ++jj) {
            int j = wave * 4 + jj;
            const float* wp = &w[OFF_W4 + j * 64 + half * 32];
            float a = 0.0f;
#pragma unroll
            for (int k = 0; k < 32; ++k) a = fmaf(hr[k], wp[k], a);
            acc[jj] = a;
        }
        __syncthreads();
#pragma unroll
        for (int jj = 0; jj < 4; ++jj) {
            int j = wave * 4 + jj;
            float s = acc[jj] + __shfl_xor(acc[jj], 32, 64);
            float v = softplus(s + w[OFF_B4 + j]);
            if (half == 0) hbuf[e][j] = v;
        }
    }
    __syncthreads();   // h4 visible

    // ---- L5: 32 -> 1, +1.0. wave 0 only.
    if (wave == 0) {
        const float* hp = &hbuf[e][half * 16];
        const float* wp = &w[OFF_W5 + half * 16];
        float a = 0.0f;
#pragma unroll
        for (int k = 0; k < 16; ++k) a = fmaf(hp[k], wp[k], a);
        float s = a + __shfl_xor(a, 32, 64);
        float v = softplus(s + w[OFF_B5]) + 1.0f;
        if (half == 0) table[blockIdx.x * 32 + e] = v;
    }
}

__device__ __forceinline__ float dg_lookup(const float* __restrict__ tab, float t) {
    const float scale = (float)(TS - 1) / 10.0f;
    float x = t * scale;
    x = fminf(fmaxf(x, 0.0f), (float)(TS - 1));
    int i = (int)x;
    if (i > TS - 2) i = TS - 2;
    float f = x - (float)i;
    float a = tab[i];
    float b = tab[i + 1];
    return fmaf(b - a, f, a);
}

// Kernel 2: per-row cumulative trapezoid with LDS-resident dg table.
// One block per row: 1024 threads x 16 elements. Two-phase: phase 1
// computes per-element increments (inc[16] regs) + per-thread sum; block
// scan; phase 2 emits with running sum. Only inc[16]+scan state live
// across the barrier -> ~50 VGPR, no spill at 16 waves/CU.
__global__ __launch_bounds__(1024, 4) void integrate(
    const float* __restrict__ t,
    const float* __restrict__ table,
    float* __restrict__ out)
{
    __shared__ float tab[TS];       // 32 KB
    __shared__ float lastt[1024];
    __shared__ float wsum[16];

    const int tid = threadIdx.x;
    // cooperative coalesced table load: 2 float4 per thread
    {
        const float4* src = (const float4*)table;
        float4* dst = (float4*)tab;
#pragma unroll
        for (int q = 0; q < TS / 4 / 1024; ++q)
            dst[q * 1024 + tid] = src[q * 1024 + tid];
    }

    const int row = blockIdx.x;
    const float* tr = t + (size_t)row * NPTS;
    float*       gr = out + (size_t)row * NPTS;
    const int base = tid * 16;

    // load 16 contiguous t values (64B-aligned float4s)
    float tv[16];
    const float4* tv4 = (const float4*)(tr + base);
#pragma unroll
    for (int q = 0; q < 4; ++q) {
        float4 v = tv4[q];
        tv[q * 4 + 0] = v.x; tv[q * 4 + 1] = v.y;
        tv[q * 4 + 2] = v.z; tv[q * 4 + 3] = v.w;
    }
    lastt[tid] = tv[15];
    __syncthreads();   // table staged + lastt visible

    // previous t (thread 0: t[0] -> dt=0 -> inc=0, matching g[0]=0)
    float tprev = (tid == 0) ? tv[0] : lastt[tid - 1];

    // phase 1: per-element increments + per-thread sum
    float inc[16];
    float s  = 0.0f;
    float tp = tprev;
    float dp = dg_lookup(tab, tprev);
#pragma unroll
    for (int q = 0; q < 16; ++q) {
        float dc = dg_lookup(tab, tv[q]);
        inc[q] = 0.5f * (dc + dp) * (tv[q] - tp);
        s += inc[q];
        tp = tv[q];
        dp = dc;
    }

    // wave-level (64-lane) inclusive scan of per-thread totals
    const int lane = tid & 63;
    const int wave = tid >> 6;
    float v = s;
#pragma unroll
    for (int d = 1; d < 64; d <<= 1) {
        float u = __shfl_up(v, d, 64);
        if (lane >= d) v += u;
    }

    // block-level scan across 16 waves
    if (lane == 63) wsum[wave] = v;
    __syncthreads();
    float woff = 0.0f;
#pragma unroll
    for (int w = 0; w < 16; ++w)
        woff += (w < wave) ? wsum[w] : 0.0f;

    // phase 2: emit with running sum
    float running = woff + (v - s);   // exclusive prefix for this thread
    float4* g4 = (float4*)(gr + base);
#pragma unroll
    for (int q = 0; q < 4; ++q) {
        float4 o;
        running += inc[q * 4 + 0]; o.x = running;
        running += inc[q * 4 + 1]; o.y = running;
        running += inc[q * 4 + 2]; o.z = running;
        running += inc[q * 4 + 3]; o.w = running;
        g4[q] = o;
    }
}

extern "C" void kernel_launch(void* const* d_in, const int* in_sizes, int n_in,
                              void* d_out, int out_size, void* d_ws, size_t ws_size,
                              hipStream_t stream)
{
    const float* t  = (const float*)d_in[0];
    const float* W1 = (const float*)d_in[1];
    const float* b1 = (const float*)d_in[2];
    const float* W2 = (const float*)d_in[3];
    const float* b2 = (const float*)d_in[4];
    const float* W3 = (const float*)d_in[5];
    const float* b3 = (const float*)d_in[6];
    const float* W4 = (const float*)d_in[7];
    const float* b4 = (const float*)d_in[8];
    const float* W5 = (const float*)d_in[9];
    const float* b5 = (const float*)d_in[10];
    float* table = (float*)d_ws;
    float* out   = (float*)d_out;

    build_table<<<TS / 32, 512, 0, stream>>>(W1, b1, W2, b2, W3, b3, W4, b4, W5, b5, table);
    integrate<<<NROWS, 1024, 0, stream>>>(t, table, out);
}